// Round 9
// baseline (209.023 us; speedup 1.0000x reference)
//
#include <hip/hip_runtime.h>

#define DIM 128
#define BN_EPS 1e-5f
#define NB 32
#define NBK_MAX 512

typedef __attribute__((ext_vector_type(8))) short bf16x8;
typedef __attribute__((ext_vector_type(4))) float f32x4;

union B8 { uint4 u; bf16x8 s; };

__device__ __forceinline__ ushort f2bf(float f) {
    unsigned u = __float_as_uint(f);
    u += 0x7fffu + ((u >> 16) & 1u);          // RNE
    return (ushort)(u >> 16);
}

// ---------------------------------------------------------------------------
// Fused prep: [0,PB) x->fp8 QUARTER-PLANAR | [PB,PB+WB) pack W | rest: bucket
// hist. Planar: plane p (3.2 MB) holds feats [32p,32p+32) of all nodes ->
// per-XCD L2-resident during the quartered gather. Blocks self-detect dtype.
// ---------------------------------------------------------------------------
__global__ void k_prep(const float4* __restrict__ x4, const float* __restrict__ Wl,
                       const float* __restrict__ Wr, const unsigned* __restrict__ eiu,
                       int* __restrict__ bcnt, uint2* __restrict__ xf8,
                       uint4* __restrict__ wpack, int nn, int ne, int PB, int WB) {
    __shared__ int nz;
    __shared__ int lh[NBK_MAX];
    int b = blockIdx.x;
    const int tid = threadIdx.x;

    if (b < PB) {                       // ---- x -> fp8 (e4m3), 8 elems/thread ----
        const int t = b * 256 + tid;
        const int n8 = nn * DIM / 8;
        if (t < n8) {
            const float4 a = x4[2 * t], c = x4[2 * t + 1];
            int u0 = __builtin_amdgcn_cvt_pk_fp8_f32(a.x, a.y, 0, false);
            u0 = __builtin_amdgcn_cvt_pk_fp8_f32(a.z, a.w, u0, true);
            int u1 = __builtin_amdgcn_cvt_pk_fp8_f32(c.x, c.y, 0, false);
            u1 = __builtin_amdgcn_cvt_pk_fp8_f32(c.z, c.w, u1, true);
            const int node = t >> 4;
            const int wd = t & 15;          // uint2-word within row
            const int p = wd >> 2, f = wd & 3;
            xf8[((size_t)p * nn + node) * 4 + f] = make_uint2((unsigned)u0, (unsigned)u1);
        }
        return;
    }
    b -= PB;
    if (b < WB) {                       // ---- pack Wl/Wr into MFMA B-fragments ----
        const int t = b * 256 + tid;    // 0..4095
        const int lane = t & 63, kk = (t >> 6) & 3, nt = (t >> 8) & 7, mat = t >> 11;
        const float* W = mat ? Wr : Wl;
        const int k0 = kk * 32 + (lane >> 4) * 8;
        const int n = nt * 16 + (lane & 15);
        ushort e[8];
#pragma unroll
        for (int j = 0; j < 8; ++j) e[j] = f2bf(W[(size_t)(k0 + j) * DIM + n]);
        uint4 o;
        o.x = ((unsigned)e[1] << 16) | e[0];
        o.y = ((unsigned)e[3] << 16) | e[2];
        o.z = ((unsigned)e[5] << 16) | e[4];
        o.w = ((unsigned)e[7] << 16) | e[6];
        wpack[t] = o;
        return;
    }
    b -= WB;                            // ---- bucket histogram (4096 edges/block) ----
    const int nbk = (nn + 255) >> 8;
    for (int i = tid; i < nbk; i += 256) lh[i] = 0;
    if (tid == 0) nz = 0;
    __syncthreads();
    const int e0 = b * 4096;
    {
        int es = e0 + tid * 16;
        if (es >= ne) es = ne - 1;
        if (eiu[2 * (size_t)es + 1] != 0) atomicOr(&nz, 1);
    }
    __syncthreads();
    const int is64 = (nz == 0);
    for (int j = 0; j < 16; ++j) {
        const int e = e0 + j * 256 + tid;
        if (e < ne) {
            int dst;
            if (is64) dst = (int)((const long long*)eiu)[(size_t)ne + e];
            else      dst = ((const int*)eiu)[(size_t)ne + e];
            atomicAdd(&lh[dst >> 8], 1);
        }
    }
    __syncthreads();
    for (int i = tid; i < nbk; i += 256)
        if (lh[i]) atomicAdd(&bcnt[i], lh[i]);
}

// ---------------------------------------------------------------------------
// Exclusive scan of bucket counts (one block, width 512 >= nbk).
// ---------------------------------------------------------------------------
__global__ __launch_bounds__(512) void k_scanb(const int* __restrict__ bcnt,
                                               int* __restrict__ bbase,
                                               int* __restrict__ cursor2, int nn, int ne) {
    __shared__ int sd[512];
    const int nbk = (nn + 255) >> 8;
    const int tid = threadIdx.x;
    const int v = (tid < nbk) ? bcnt[tid] : 0;
    sd[tid] = v;
    __syncthreads();
    for (int ofs = 1; ofs < 512; ofs <<= 1) {
        const int t = (tid >= ofs) ? sd[tid - ofs] : 0;
        __syncthreads();
        sd[tid] += t;
        __syncthreads();
    }
    if (tid < nbk) {
        const int ex = sd[tid] - v;
        bbase[tid] = ex;
        cursor2[tid] = ex;
    }
    if (tid == 0) bbase[nbk] = ne;
}

// ---------------------------------------------------------------------------
// Pass A: partition edges into buckets (packed (local<<24|src) u32).
// ---------------------------------------------------------------------------
__global__ __launch_bounds__(256) void k_passA(const unsigned* __restrict__ eiu,
                                               int* __restrict__ cursor2,
                                               unsigned* __restrict__ pairbuf,
                                               int nn, int ne) {
    __shared__ int lh[NBK_MAX];
    __shared__ int gb[NBK_MAX];
    __shared__ int nz;
    const int nbk = (nn + 255) >> 8;
    const int tid = threadIdx.x;
    const int e0 = blockIdx.x * 4096;
    for (int i = tid; i < nbk; i += 256) lh[i] = 0;
    if (tid == 0) nz = 0;
    __syncthreads();
    {
        int es = e0 + tid * 16;
        if (es >= ne) es = ne - 1;
        if (eiu[2 * (size_t)es + 1] != 0) atomicOr(&nz, 1);
    }
    __syncthreads();
    const int is64 = (nz == 0);
    unsigned pay[16];
    int bkrank[16];
#pragma unroll
    for (int j = 0; j < 16; ++j) {
        const int e = e0 + j * 256 + tid;
        bkrank[j] = -1;
        if (e < ne) {
            int src, dst;
            if (is64) {
                const long long* p = (const long long*)eiu;
                src = (int)p[e];
                dst = (int)p[(size_t)ne + e];
            } else {
                const int* p = (const int*)eiu;
                src = p[e];
                dst = p[(size_t)ne + e];
            }
            const int bk = dst >> 8;
            const int rank = atomicAdd(&lh[bk], 1);
            bkrank[j] = (bk << 16) | rank;
            pay[j] = ((unsigned)(dst & 255) << 24) | (unsigned)src;
        }
    }
    __syncthreads();
    for (int i = tid; i < nbk; i += 256) {
        const int c = lh[i];
        gb[i] = c ? atomicAdd(&cursor2[i], c) : 0;
    }
    __syncthreads();
#pragma unroll
    for (int j = 0; j < 16; ++j) {
        if (bkrank[j] >= 0) {
            const int bk = bkrank[j] >> 16, rank = bkrank[j] & 0xFFFF;
            pairbuf[gb[bk] + rank] = pay[j];
        }
    }
}

// ---------------------------------------------------------------------------
// Pass B: per bucket (256 nodes): per-node CSR within contiguous window.
// ---------------------------------------------------------------------------
__global__ __launch_bounds__(256) void k_passB(const unsigned* __restrict__ pairbuf,
                                               const int* __restrict__ bbase,
                                               int* __restrict__ off, int* __restrict__ cnt,
                                               int* __restrict__ srcbuf, int nn) {
    __shared__ int cl[256];
    __shared__ int sd[256];
    __shared__ int cur[256];
    const int tid = threadIdx.x;
    const int b = blockIdx.x;
    const int node0 = b << 8;
    const int e0 = bbase[b], e1 = bbase[b + 1];
    cl[tid] = 0;
    __syncthreads();
    for (int e = e0 + tid; e < e1; e += 256)
        atomicAdd(&cl[pairbuf[e] >> 24], 1);
    __syncthreads();
    const int v = cl[tid];
    sd[tid] = v;
    __syncthreads();
    for (int ofs = 1; ofs < 256; ofs <<= 1) {
        const int t = (tid >= ofs) ? sd[tid - ofs] : 0;
        __syncthreads();
        sd[tid] += t;
        __syncthreads();
    }
    const int ex = sd[tid] - v;
    cur[tid] = ex;
    const int node = node0 + tid;
    if (node < nn) {
        off[node] = e0 + ex;
        cnt[node] = v;
    }
    __syncthreads();
    for (int e = e0 + tid; e < e1; e += 256) {
        const unsigned p = pairbuf[e];
        const int pos = atomicAdd(&cur[p >> 24], 1);
        srcbuf[e0 + pos] = (int)(p & 0xFFFFFFu);
    }
}

// ---------------------------------------------------------------------------
// Fused: quartered fp8 gather-mean + dual bf16 MFMA GEMM + relu + BN partials.
// 512 threads = 8 waves; NB=32 nodes; 16-lane group owns one node.
// Gather runs 4 feature-quarter passes; in pass p only plane p (3.2 MB,
// L2-resident) is touched. Group = 4 edge-slots (es) x 4 feature-lanes (f);
// lane loads uint2 = 8 fp8 feats; acc[8] f32; combine via shfl_xor(4,8).
// ---------------------------------------------------------------------------
__global__ __launch_bounds__(512, 4) void k_gemm(
    const float4* __restrict__ x4g, const uint2* __restrict__ xf8,
    const uint4* __restrict__ wpack, const float* __restrict__ bl,
    const int* __restrict__ off, const int* __restrict__ cnt,
    const int* __restrict__ srcbuf,
    ushort* __restrict__ hout, float* __restrict__ ssum, float* __restrict__ ssq,
    int nn)
{
    __shared__ uint4 mean4[NB * 16];
    __shared__ uint4 xls4[NB * 16];
    __shared__ float red_sum[2][DIM];
    __shared__ float red_sq[2][DIM];

    const int tid = threadIdx.x;
    const int lane = tid & 63;
    const int w = tid >> 6;
    const int base = blockIdx.x * NB;
    const int q = lane & 15;
    const int es = q >> 2;        // edge slot 0..3
    const int f = q & 3;          // uint2 word within quarter

#define CVT8(v)                                                           \
    {                                                                     \
        auto p0 = __builtin_amdgcn_cvt_pk_f32_fp8((v).x, false);          \
        auto p1 = __builtin_amdgcn_cvt_pk_f32_fp8((v).x, true);           \
        auto p2 = __builtin_amdgcn_cvt_pk_f32_fp8((v).y, false);          \
        auto p3 = __builtin_amdgcn_cvt_pk_f32_fp8((v).y, true);           \
        acc[0] += p0[0]; acc[1] += p0[1]; acc[2] += p1[0]; acc[3] += p1[1]; \
        acc[4] += p2[0]; acc[5] += p2[1]; acc[6] += p3[0]; acc[7] += p3[1]; \
    }

    // ---- gather-mean: group owns node ln = w*4 + (lane>>4) ----
    {
        const int ln = w * 4 + (lane >> 4);
        const int node = base + ln;
        uint4 xp = make_uint4(0, 0, 0, 0);
        int o = 0, c = 0;
        if (node < nn) {
            const float4 xa = x4g[(size_t)node * 32 + 2 * q];
            const float4 xb = x4g[(size_t)node * 32 + 2 * q + 1];
            xp.x = ((unsigned)f2bf(xa.y) << 16) | f2bf(xa.x);
            xp.y = ((unsigned)f2bf(xa.w) << 16) | f2bf(xa.z);
            xp.z = ((unsigned)f2bf(xb.y) << 16) | f2bf(xb.x);
            xp.w = ((unsigned)f2bf(xb.w) << 16) | f2bf(xb.z);
            o = off[node];
            c = cnt[node];
        }
        xls4[ln * 16 + (q ^ (ln & 15))] = xp;
        const float r = 1.0f / fmaxf((float)c, 1.0f);

#pragma unroll
        for (int p = 0; p < 4; ++p) {
            const uint2* __restrict__ plane = xf8 + (size_t)p * nn * 4;
            float acc[8];
#pragma unroll
            for (int j = 0; j < 8; ++j) acc[j] = 0.f;
            if (node < nn) {             // wave-uniform
                int e = 0;
                for (; e + 8 <= c; e += 8) {
                    const int s0 = srcbuf[o + e + es];
                    const int s1 = srcbuf[o + e + 4 + es];
                    const uint2 v0 = plane[(size_t)s0 * 4 + f];
                    const uint2 v1 = plane[(size_t)s1 * 4 + f];
                    CVT8(v0);
                    CVT8(v1);
                }
                for (; e + 4 <= c; e += 4) {
                    const int s = srcbuf[o + e + es];
                    const uint2 v = plane[(size_t)s * 4 + f];
                    CVT8(v);
                }
                const int rem = c - e;
                if (es < rem) {
                    const int s = srcbuf[o + e + es];
                    const uint2 v = plane[(size_t)s * 4 + f];
                    CVT8(v);
                }
            }
#pragma unroll
            for (int j = 0; j < 8; ++j) {
                acc[j] += __shfl_xor(acc[j], 4);
                acc[j] += __shfl_xor(acc[j], 8);
                acc[j] *= r;
            }
            if (es == 0) {               // 4 lanes/group write this quarter
                uint4 mp;
                mp.x = ((unsigned)f2bf(acc[1]) << 16) | f2bf(acc[0]);
                mp.y = ((unsigned)f2bf(acc[3]) << 16) | f2bf(acc[2]);
                mp.z = ((unsigned)f2bf(acc[5]) << 16) | f2bf(acc[4]);
                mp.w = ((unsigned)f2bf(acc[7]) << 16) | f2bf(acc[6]);
                mean4[ln * 16 + ((p * 4 + f) ^ (ln & 15))] = mp;
            }
        }
    }
#undef CVT8
    __syncthreads();

    // ---- MFMA phase: wave w -> m = w&1, n-tiles nh*2 + {0,1} ----
    const int m = w & 1;
    const int nh = w >> 1;
    const int row16 = lane & 15;
    const int kgrp = lane >> 4;
    const int ln2 = m * 16 + row16;

    bf16x8 am[4], ax[4];
#pragma unroll
    for (int kk = 0; kk < 4; ++kk) {
        const int unit = (kk * 4 + kgrp) ^ row16;
        B8 va, vb;
        va.u = mean4[ln2 * 16 + unit];
        vb.u = xls4[ln2 * 16 + unit];
        am[kk] = va.s;
        ax[kk] = vb.s;
    }

    f32x4 acc2[2];
#pragma unroll
    for (int j = 0; j < 2; ++j) {
        const float bv = bl[(nh * 2 + j) * 16 + row16];
        acc2[j] = (f32x4){bv, bv, bv, bv};
    }

#pragma unroll
    for (int j = 0; j < 2; ++j) {
        const int nt = nh * 2 + j;
        const uint4* pl = wpack + (size_t)(nt * 4) * 64 + lane;
        const uint4* pr = wpack + (size_t)((8 + nt) * 4) * 64 + lane;
        B8 wl[4], wr[4];
#pragma unroll
        for (int kk = 0; kk < 4; ++kk) {
            wl[kk].u = pl[kk * 64];
            wr[kk].u = pr[kk * 64];
        }
#pragma unroll
        for (int kk = 0; kk < 4; ++kk)
            acc2[j] = __builtin_amdgcn_mfma_f32_16x16x32_bf16(am[kk], wl[kk].s, acc2[j], 0, 0, 0);
#pragma unroll
        for (int kk = 0; kk < 4; ++kk)
            acc2[j] = __builtin_amdgcn_mfma_f32_16x16x32_bf16(ax[kk], wr[kk].s, acc2[j], 0, 0, 0);
    }

    // ---- relu + store h (bf16) + BN partials ----
#pragma unroll
    for (int j = 0; j < 2; ++j) {
        const int feat = (nh * 2 + j) * 16 + row16;
        float s = 0.f, sq = 0.f;
#pragma unroll
        for (int r = 0; r < 4; ++r) {
            const int node = base + m * 16 + kgrp * 4 + r;
            const float v = fmaxf(acc2[j][r], 0.0f);
            if (node < nn) {
                hout[(size_t)node * DIM + feat] = f2bf(v);
                s += v;
                sq += v * v;
            }
        }
        s += __shfl_xor(s, 16);
        s += __shfl_xor(s, 32);
        sq += __shfl_xor(sq, 16);
        sq += __shfl_xor(sq, 32);
        if (lane < 16) {
            red_sum[m][feat] = s;
            red_sq[m][feat] = sq;
        }
    }
    __syncthreads();
    if (tid < DIM) {
        atomicAdd(&ssum[tid], red_sum[0][tid] + red_sum[1][tid]);
        atomicAdd(&ssq[tid], red_sq[0][tid] + red_sq[1][tid]);
    }
}

// ---------------------------------------------------------------------------
// Finalize: out = x + (h - mu) * rsqrt(var+eps) * gamma + beta; h bf16.
// Grid aligned with k_gemm tiles so hbuf reads are XCD-local.
// ---------------------------------------------------------------------------
__global__ __launch_bounds__(512) void k_finalize(
    const float4* __restrict__ x4, const uint4* __restrict__ h4,
    const float* __restrict__ ssum, const float* __restrict__ ssq,
    const float* __restrict__ gamma, const float* __restrict__ beta,
    float4* __restrict__ out4, int nn)
{
    const float invN = 1.0f / (float)nn;
    const int tid = threadIdx.x;
    const int node = blockIdx.x * 32 + (tid >> 4);
    const int q = tid & 15;
    if (node >= nn) return;
    const uint4 hv = h4[(size_t)node * 16 + q];
    const float4 xa = x4[(size_t)node * 32 + 2 * q];
    const float4 xb = x4[(size_t)node * 32 + 2 * q + 1];
    const float4 s4a = ((const float4*)ssum)[2 * q], s4b = ((const float4*)ssum)[2 * q + 1];
    const float4 q4a = ((const float4*)ssq)[2 * q], q4b = ((const float4*)ssq)[2 * q + 1];
    const float4 g4a = ((const float4*)gamma)[2 * q], g4b = ((const float4*)gamma)[2 * q + 1];
    const float4 b4a = ((const float4*)beta)[2 * q], b4b = ((const float4*)beta)[2 * q + 1];
    float h[8];
    h[0] = __uint_as_float(hv.x << 16);
    h[1] = __uint_as_float(hv.x & 0xffff0000u);
    h[2] = __uint_as_float(hv.y << 16);
    h[3] = __uint_as_float(hv.y & 0xffff0000u);
    h[4] = __uint_as_float(hv.z << 16);
    h[5] = __uint_as_float(hv.z & 0xffff0000u);
    h[6] = __uint_as_float(hv.w << 16);
    h[7] = __uint_as_float(hv.w & 0xffff0000u);
    float4 oa, ob;
    {
        const float mu = s4a.x * invN, rs = rsqrtf(q4a.x * invN - mu * mu + BN_EPS);
        oa.x = xa.x + (h[0] - mu) * rs * g4a.x + b4a.x;
    }
    {
        const float mu = s4a.y * invN, rs = rsqrtf(q4a.y * invN - mu * mu + BN_EPS);
        oa.y = xa.y + (h[1] - mu) * rs * g4a.y + b4a.y;
    }
    {
        const float mu = s4a.z * invN, rs = rsqrtf(q4a.z * invN - mu * mu + BN_EPS);
        oa.z = xa.z + (h[2] - mu) * rs * g4a.z + b4a.z;
    }
    {
        const float mu = s4a.w * invN, rs = rsqrtf(q4a.w * invN - mu * mu + BN_EPS);
        oa.w = xa.w + (h[3] - mu) * rs * g4a.w + b4a.w;
    }
    {
        const float mu = s4b.x * invN, rs = rsqrtf(q4b.x * invN - mu * mu + BN_EPS);
        ob.x = xb.x + (h[4] - mu) * rs * g4b.x + b4b.x;
    }
    {
        const float mu = s4b.y * invN, rs = rsqrtf(q4b.y * invN - mu * mu + BN_EPS);
        ob.y = xb.y + (h[5] - mu) * rs * g4b.y + b4b.y;
    }
    {
        const float mu = s4b.z * invN, rs = rsqrtf(q4b.z * invN - mu * mu + BN_EPS);
        ob.z = xb.z + (h[6] - mu) * rs * g4b.z + b4b.z;
    }
    {
        const float mu = s4b.w * invN, rs = rsqrtf(q4b.w * invN - mu * mu + BN_EPS);
        ob.w = xb.w + (h[7] - mu) * rs * g4b.w + b4b.w;
    }
    out4[(size_t)node * 32 + 2 * q] = oa;
    out4[(size_t)node * 32 + 2 * q + 1] = ob;
}

extern "C" void kernel_launch(void* const* d_in, const int* in_sizes, int n_in,
                              void* d_out, int out_size, void* d_ws, size_t ws_size,
                              hipStream_t stream) {
    const float* x     = (const float*)d_in[0];
    const void*  ei    = d_in[1];
    const float* Wl    = (const float*)d_in[2];
    const float* bl    = (const float*)d_in[3];
    const float* Wr    = (const float*)d_in[4];
    const float* gamma = (const float*)d_in[5];
    const float* beta  = (const float*)d_in[6];
    float* out = (float*)d_out;

    const int nn = in_sizes[0] / DIM;   // 100000
    const int ne = in_sizes[1] / 2;     // 1600000
    const int nbk = (nn + 255) >> 8;    // 391

    // workspace layout (~46 MB)
    int* ws = (int*)d_ws;
    int*   bcnt    = ws;                 // 512
    float* ssum    = (float*)(ws + 512); // 128
    float* ssq     = (float*)(ws + 640); // 128
    int*   bbase   = ws + 768;           // 512 (nbk+1)
    int*   cursor2 = ws + 1280;          // 512
    int*   cnt     = ws + 1792;          // nn
    int*   off     = cnt + nn;           // nn
    size_t pos = 1792 + 2 * (size_t)nn;
    pos = (pos + 3) & ~(size_t)3;
    uint4* wpack  = (uint4*)(ws + pos);          // 4096 uint4
    int*   srcbuf = (int*)(wpack + 4096);        // ne
    size_t p2 = (size_t)(srcbuf + ne - ws);
    p2 = (p2 + 3) & ~(size_t)3;
    uint2* xf8 = (uint2*)(ws + p2);              // nn*16 uint2 (quarter-planar)
    // union region: pairbuf (passA/passB) then hbuf (gemm/finalize)
    unsigned* pairbuf = (unsigned*)(xf8 + (size_t)nn * 16);  // ne u32
    ushort*   hbuf    = (ushort*)pairbuf;                    // nn*128 bf16

    hipMemsetAsync(d_ws, 0, 768 * sizeof(int), stream);  // bcnt + ssum + ssq

    const int PB = (nn * DIM / 8 + 255) / 256;   // 6250
    const int WB = 16;
    const int HB = (ne + 4095) / 4096;           // 391
    k_prep<<<PB + WB + HB, 256, 0, stream>>>((const float4*)x, Wl, Wr,
                                             (const unsigned*)ei, bcnt, xf8, wpack,
                                             nn, ne, PB, WB);
    k_scanb<<<1, 512, 0, stream>>>(bcnt, bbase, cursor2, nn, ne);
    k_passA<<<(ne + 4095) / 4096, 256, 0, stream>>>((const unsigned*)ei, cursor2,
                                                    pairbuf, nn, ne);
    k_passB<<<nbk, 256, 0, stream>>>(pairbuf, bbase, off, cnt, srcbuf, nn);
    const int ntile = (nn + NB - 1) / NB;        // 3125
    k_gemm<<<ntile, 512, 0, stream>>>((const float4*)x, xf8, wpack, bl,
                                      off, cnt, srcbuf, hbuf, ssum, ssq, nn);
    k_finalize<<<ntile, 512, 0, stream>>>((const float4*)x, (const uint4*)hbuf,
                                          ssum, ssq, gamma, beta, (float4*)out, nn);
}

// Round 10
// 184.413 us; speedup vs baseline: 1.1334x; 1.1334x over previous
//
#include <hip/hip_runtime.h>

#define DIM 128
#define BN_EPS 1e-5f
#define NB 32
#define NBK_MAX 512

typedef __attribute__((ext_vector_type(8))) short bf16x8;
typedef __attribute__((ext_vector_type(4))) float f32x4;

union B8 { uint4 u; bf16x8 s; };

__device__ __forceinline__ ushort f2bf(float f) {
    unsigned u = __float_as_uint(f);
    u += 0x7fffu + ((u >> 16) & 1u);          // RNE
    return (ushort)(u >> 16);
}

// ---------------------------------------------------------------------------
// Fused prep: [0,PB) x->fp8 row-major + x->bf16 copy | [PB,PB+WB) pack W |
// [PB+WB,+HB) bucket hist (dst>>8). Blocks self-detect int64 vs int32.
// ---------------------------------------------------------------------------
__global__ void k_prep(const float4* __restrict__ x4, const float* __restrict__ Wl,
                       const float* __restrict__ Wr, const unsigned* __restrict__ eiu,
                       int* __restrict__ bcnt, uint2* __restrict__ xf8,
                       uint4* __restrict__ xbf, uint4* __restrict__ wpack,
                       int nn, int ne, int PB, int WB) {
    __shared__ int nz;
    __shared__ int lh[NBK_MAX];
    int b = blockIdx.x;
    const int tid = threadIdx.x;

    if (b < PB) {                       // ---- x -> fp8 + bf16, 8 elems/thread ----
        const int t = b * 256 + tid;
        const int n8 = nn * DIM / 8;
        if (t < n8) {
            const float4 a = x4[2 * t], c = x4[2 * t + 1];
            int u0 = __builtin_amdgcn_cvt_pk_fp8_f32(a.x, a.y, 0, false);
            u0 = __builtin_amdgcn_cvt_pk_fp8_f32(a.z, a.w, u0, true);
            int u1 = __builtin_amdgcn_cvt_pk_fp8_f32(c.x, c.y, 0, false);
            u1 = __builtin_amdgcn_cvt_pk_fp8_f32(c.z, c.w, u1, true);
            xf8[t] = make_uint2((unsigned)u0, (unsigned)u1);
            uint4 xb;
            xb.x = ((unsigned)f2bf(a.y) << 16) | f2bf(a.x);
            xb.y = ((unsigned)f2bf(a.w) << 16) | f2bf(a.z);
            xb.z = ((unsigned)f2bf(c.y) << 16) | f2bf(c.x);
            xb.w = ((unsigned)f2bf(c.w) << 16) | f2bf(c.z);
            xbf[t] = xb;
        }
        return;
    }
    b -= PB;
    if (b < WB) {                       // ---- pack Wl/Wr into MFMA B-fragments ----
        const int t = b * 256 + tid;    // 0..4095
        const int lane = t & 63, kk = (t >> 6) & 3, nt = (t >> 8) & 7, mat = t >> 11;
        const float* W = mat ? Wr : Wl;
        const int k0 = kk * 32 + (lane >> 4) * 8;
        const int n = nt * 16 + (lane & 15);
        ushort e[8];
#pragma unroll
        for (int j = 0; j < 8; ++j) e[j] = f2bf(W[(size_t)(k0 + j) * DIM + n]);
        uint4 o;
        o.x = ((unsigned)e[1] << 16) | e[0];
        o.y = ((unsigned)e[3] << 16) | e[2];
        o.z = ((unsigned)e[5] << 16) | e[4];
        o.w = ((unsigned)e[7] << 16) | e[6];
        wpack[t] = o;
        return;
    }
    b -= WB;                            // ---- bucket histogram (4096 edges/block) ----
    const int nbk = (nn + 255) >> 8;
    for (int i = tid; i < nbk; i += 256) lh[i] = 0;
    if (tid == 0) nz = 0;
    __syncthreads();
    const int e0 = b * 4096;
    {
        int es = e0 + tid * 16;
        if (es >= ne) es = ne - 1;
        if (eiu[2 * (size_t)es + 1] != 0) atomicOr(&nz, 1);
    }
    __syncthreads();
    const int is64 = (nz == 0);
    for (int j = 0; j < 16; ++j) {
        const int e = e0 + j * 256 + tid;
        if (e < ne) {
            int dst;
            if (is64) dst = (int)((const long long*)eiu)[(size_t)ne + e];
            else      dst = ((const int*)eiu)[(size_t)ne + e];
            atomicAdd(&lh[dst >> 8], 1);
        }
    }
    __syncthreads();
    for (int i = tid; i < nbk; i += 256)
        if (lh[i]) atomicAdd(&bcnt[i], lh[i]);
}

// ---------------------------------------------------------------------------
// Exclusive scan of bucket counts (one block, width 512 >= nbk).
// ---------------------------------------------------------------------------
__global__ __launch_bounds__(512) void k_scanb(const int* __restrict__ bcnt,
                                               int* __restrict__ bbase,
                                               int* __restrict__ cursor2, int nn, int ne) {
    __shared__ int sd[512];
    const int nbk = (nn + 255) >> 8;
    const int tid = threadIdx.x;
    const int v = (tid < nbk) ? bcnt[tid] : 0;
    sd[tid] = v;
    __syncthreads();
    for (int ofs = 1; ofs < 512; ofs <<= 1) {
        const int t = (tid >= ofs) ? sd[tid - ofs] : 0;
        __syncthreads();
        sd[tid] += t;
        __syncthreads();
    }
    if (tid < nbk) {
        const int ex = sd[tid] - v;
        bbase[tid] = ex;
        cursor2[tid] = ex;
    }
    if (tid == 0) bbase[nbk] = ne;
}

// ---------------------------------------------------------------------------
// Pass A: partition edges into buckets (packed (local<<24|src) u32).
// ---------------------------------------------------------------------------
__global__ __launch_bounds__(256) void k_passA(const unsigned* __restrict__ eiu,
                                               int* __restrict__ cursor2,
                                               unsigned* __restrict__ pairbuf,
                                               int nn, int ne) {
    __shared__ int lh[NBK_MAX];
    __shared__ int gb[NBK_MAX];
    __shared__ int nz;
    const int nbk = (nn + 255) >> 8;
    const int tid = threadIdx.x;
    const int e0 = blockIdx.x * 4096;
    for (int i = tid; i < nbk; i += 256) lh[i] = 0;
    if (tid == 0) nz = 0;
    __syncthreads();
    {
        int es = e0 + tid * 16;
        if (es >= ne) es = ne - 1;
        if (eiu[2 * (size_t)es + 1] != 0) atomicOr(&nz, 1);
    }
    __syncthreads();
    const int is64 = (nz == 0);
    unsigned pay[16];
    int bkrank[16];
#pragma unroll
    for (int j = 0; j < 16; ++j) {
        const int e = e0 + j * 256 + tid;
        bkrank[j] = -1;
        if (e < ne) {
            int src, dst;
            if (is64) {
                const long long* p = (const long long*)eiu;
                src = (int)p[e];
                dst = (int)p[(size_t)ne + e];
            } else {
                const int* p = (const int*)eiu;
                src = p[e];
                dst = p[(size_t)ne + e];
            }
            const int bk = dst >> 8;
            const int rank = atomicAdd(&lh[bk], 1);
            bkrank[j] = (bk << 16) | rank;
            pay[j] = ((unsigned)(dst & 255) << 24) | (unsigned)src;
        }
    }
    __syncthreads();
    for (int i = tid; i < nbk; i += 256) {
        const int c = lh[i];
        gb[i] = c ? atomicAdd(&cursor2[i], c) : 0;
    }
    __syncthreads();
#pragma unroll
    for (int j = 0; j < 16; ++j) {
        if (bkrank[j] >= 0) {
            const int bk = bkrank[j] >> 16, rank = bkrank[j] & 0xFFFF;
            pairbuf[gb[bk] + rank] = pay[j];
        }
    }
}

// ---------------------------------------------------------------------------
// Pass B: per bucket (256 nodes): per-node CSR within contiguous window.
// ---------------------------------------------------------------------------
__global__ __launch_bounds__(256) void k_passB(const unsigned* __restrict__ pairbuf,
                                               const int* __restrict__ bbase,
                                               int* __restrict__ off, int* __restrict__ cnt,
                                               int* __restrict__ srcbuf, int nn) {
    __shared__ int cl[256];
    __shared__ int sd[256];
    __shared__ int cur[256];
    const int tid = threadIdx.x;
    const int b = blockIdx.x;
    const int node0 = b << 8;
    const int e0 = bbase[b], e1 = bbase[b + 1];
    cl[tid] = 0;
    __syncthreads();
    for (int e = e0 + tid; e < e1; e += 256)
        atomicAdd(&cl[pairbuf[e] >> 24], 1);
    __syncthreads();
    const int v = cl[tid];
    sd[tid] = v;
    __syncthreads();
    for (int ofs = 1; ofs < 256; ofs <<= 1) {
        const int t = (tid >= ofs) ? sd[tid - ofs] : 0;
        __syncthreads();
        sd[tid] += t;
        __syncthreads();
    }
    const int ex = sd[tid] - v;
    cur[tid] = ex;
    const int node = node0 + tid;
    if (node < nn) {
        off[node] = e0 + ex;
        cnt[node] = v;
    }
    __syncthreads();
    for (int e = e0 + tid; e < e1; e += 256) {
        const unsigned p = pairbuf[e];
        const int pos = atomicAdd(&cur[p >> 24], 1);
        srcbuf[e0 + pos] = (int)(p & 0xFFFFFFu);
    }
}

// ---------------------------------------------------------------------------
// Fused: fp8 gather-mean + dual bf16 MFMA GEMM + bias + relu + BN partials.
// 512 threads = 8 waves; NB=32 nodes. GATHER (R7 structure, 8-deep): 16-lane
// group owns one node; lane q holds feature octet [8q,8q+8); 8 edges' idx +
// row loads issued before any convert -> 8 outstanding row-loads per lane.
// ---------------------------------------------------------------------------
__global__ __launch_bounds__(512, 4) void k_gemm(
    const uint4* __restrict__ xbf, const uint2* __restrict__ xf8,
    const uint4* __restrict__ wpack, const float* __restrict__ bl,
    const int* __restrict__ off, const int* __restrict__ cnt,
    const int* __restrict__ srcbuf,
    ushort* __restrict__ hout, float* __restrict__ ssum, float* __restrict__ ssq,
    int nn)
{
    __shared__ uint4 mean4[NB * 16];
    __shared__ uint4 xls4[NB * 16];
    __shared__ float red_sum[2][DIM];
    __shared__ float red_sq[2][DIM];

    const int tid = threadIdx.x;
    const int lane = tid & 63;
    const int w = tid >> 6;
    const int base = blockIdx.x * NB;
    const int q = lane & 15;      // feature octet

#define CVT8(v)                                                           \
    {                                                                     \
        auto p0 = __builtin_amdgcn_cvt_pk_f32_fp8((v).x, false);          \
        auto p1 = __builtin_amdgcn_cvt_pk_f32_fp8((v).x, true);           \
        auto p2 = __builtin_amdgcn_cvt_pk_f32_fp8((v).y, false);          \
        auto p3 = __builtin_amdgcn_cvt_pk_f32_fp8((v).y, true);           \
        acc[0] += p0[0]; acc[1] += p0[1]; acc[2] += p1[0]; acc[3] += p1[1]; \
        acc[4] += p2[0]; acc[5] += p2[1]; acc[6] += p3[0]; acc[7] += p3[1]; \
    }

    // ---- gather-mean: group owns node ln = w*4 + (lane>>4) ----
    {
        const int ln = w * 4 + (lane >> 4);
        const int node = base + ln;
        float acc[8];
#pragma unroll
        for (int j = 0; j < 8; ++j) acc[j] = 0.f;
        uint4 xp = make_uint4(0, 0, 0, 0);

        if (node < nn) {                 // wave-uniform branch
            xp = xbf[(size_t)node * 16 + q];      // self row, bf16 direct

            const int o = off[node];
            const int c = cnt[node];
            int e = 0;
            for (; e + 8 <= c; e += 8) {          // 8 rows in flight
                const int s0 = srcbuf[o + e + 0];
                const int s1 = srcbuf[o + e + 1];
                const int s2 = srcbuf[o + e + 2];
                const int s3 = srcbuf[o + e + 3];
                const int s4 = srcbuf[o + e + 4];
                const int s5 = srcbuf[o + e + 5];
                const int s6 = srcbuf[o + e + 6];
                const int s7 = srcbuf[o + e + 7];
                const uint2 v0 = xf8[(size_t)s0 * 16 + q];
                const uint2 v1 = xf8[(size_t)s1 * 16 + q];
                const uint2 v2 = xf8[(size_t)s2 * 16 + q];
                const uint2 v3 = xf8[(size_t)s3 * 16 + q];
                const uint2 v4 = xf8[(size_t)s4 * 16 + q];
                const uint2 v5 = xf8[(size_t)s5 * 16 + q];
                const uint2 v6 = xf8[(size_t)s6 * 16 + q];
                const uint2 v7 = xf8[(size_t)s7 * 16 + q];
                CVT8(v0); CVT8(v1); CVT8(v2); CVT8(v3);
                CVT8(v4); CVT8(v5); CVT8(v6); CVT8(v7);
            }
            for (; e + 4 <= c; e += 4) {
                const int s0 = srcbuf[o + e + 0];
                const int s1 = srcbuf[o + e + 1];
                const int s2 = srcbuf[o + e + 2];
                const int s3 = srcbuf[o + e + 3];
                const uint2 v0 = xf8[(size_t)s0 * 16 + q];
                const uint2 v1 = xf8[(size_t)s1 * 16 + q];
                const uint2 v2 = xf8[(size_t)s2 * 16 + q];
                const uint2 v3 = xf8[(size_t)s3 * 16 + q];
                CVT8(v0); CVT8(v1); CVT8(v2); CVT8(v3);
            }
            for (; e < c; ++e) {
                const int s = srcbuf[o + e];
                const uint2 v = xf8[(size_t)s * 16 + q];
                CVT8(v);
            }
            const float r = 1.0f / fmaxf((float)c, 1.0f);
#pragma unroll
            for (int j = 0; j < 8; ++j) acc[j] *= r;
        }
#undef CVT8

        const int slot = q ^ (ln & 15);
        xls4[ln * 16 + slot] = xp;
        uint4 mp;
        mp.x = ((unsigned)f2bf(acc[1]) << 16) | f2bf(acc[0]);
        mp.y = ((unsigned)f2bf(acc[3]) << 16) | f2bf(acc[2]);
        mp.z = ((unsigned)f2bf(acc[5]) << 16) | f2bf(acc[4]);
        mp.w = ((unsigned)f2bf(acc[7]) << 16) | f2bf(acc[6]);
        mean4[ln * 16 + slot] = mp;
    }
    __syncthreads();

    // ---- MFMA phase: wave w -> m = w&1, n-tiles nh*2 + {0,1} ----
    const int m = w & 1;
    const int nh = w >> 1;
    const int row16 = lane & 15;
    const int kgrp = lane >> 4;
    const int ln2 = m * 16 + row16;

    bf16x8 am[4], ax[4];
#pragma unroll
    for (int kk = 0; kk < 4; ++kk) {
        const int unit = (kk * 4 + kgrp) ^ row16;
        B8 va, vb;
        va.u = mean4[ln2 * 16 + unit];
        vb.u = xls4[ln2 * 16 + unit];
        am[kk] = va.s;
        ax[kk] = vb.s;
    }

    f32x4 acc2[2];
#pragma unroll
    for (int j = 0; j < 2; ++j) {
        const float bv = bl[(nh * 2 + j) * 16 + row16];
        acc2[j] = (f32x4){bv, bv, bv, bv};
    }

#pragma unroll
    for (int j = 0; j < 2; ++j) {
        const int nt = nh * 2 + j;
        const uint4* pl = wpack + (size_t)(nt * 4) * 64 + lane;
        const uint4* pr = wpack + (size_t)((8 + nt) * 4) * 64 + lane;
        B8 wl[4], wr[4];
#pragma unroll
        for (int kk = 0; kk < 4; ++kk) {
            wl[kk].u = pl[kk * 64];
            wr[kk].u = pr[kk * 64];
        }
#pragma unroll
        for (int kk = 0; kk < 4; ++kk)
            acc2[j] = __builtin_amdgcn_mfma_f32_16x16x32_bf16(am[kk], wl[kk].s, acc2[j], 0, 0, 0);
#pragma unroll
        for (int kk = 0; kk < 4; ++kk)
            acc2[j] = __builtin_amdgcn_mfma_f32_16x16x32_bf16(ax[kk], wr[kk].s, acc2[j], 0, 0, 0);
    }

    // ---- relu + store h (bf16) + BN partials ----
#pragma unroll
    for (int j = 0; j < 2; ++j) {
        const int feat = (nh * 2 + j) * 16 + row16;
        float s = 0.f, sq = 0.f;
#pragma unroll
        for (int r = 0; r < 4; ++r) {
            const int node = base + m * 16 + kgrp * 4 + r;
            const float v = fmaxf(acc2[j][r], 0.0f);
            if (node < nn) {
                hout[(size_t)node * DIM + feat] = f2bf(v);
                s += v;
                sq += v * v;
            }
        }
        s += __shfl_xor(s, 16);
        s += __shfl_xor(s, 32);
        sq += __shfl_xor(sq, 16);
        sq += __shfl_xor(sq, 32);
        if (lane < 16) {
            red_sum[m][feat] = s;
            red_sq[m][feat] = sq;
        }
    }
    __syncthreads();
    if (tid < DIM) {
        atomicAdd(&ssum[tid], red_sum[0][tid] + red_sum[1][tid]);
        atomicAdd(&ssq[tid], red_sq[0][tid] + red_sq[1][tid]);
    }
}

// ---------------------------------------------------------------------------
// Finalize: out = x + (h - mu) * rsqrt(var+eps) * gamma + beta; h,x both bf16.
// Grid aligned with k_gemm tiles so hbuf/xbf reads are L2-warm.
// ---------------------------------------------------------------------------
__global__ __launch_bounds__(512) void k_finalize(
    const uint4* __restrict__ xbf, const uint4* __restrict__ h4,
    const float* __restrict__ ssum, const float* __restrict__ ssq,
    const float* __restrict__ gamma, const float* __restrict__ beta,
    float4* __restrict__ out4, int nn)
{
    const float invN = 1.0f / (float)nn;
    const int tid = threadIdx.x;
    const int node = blockIdx.x * 32 + (tid >> 4);
    const int q = tid & 15;
    if (node >= nn) return;
    const uint4 hv = h4[(size_t)node * 16 + q];
    const uint4 xv = xbf[(size_t)node * 16 + q];
    const float4 s4a = ((const float4*)ssum)[2 * q], s4b = ((const float4*)ssum)[2 * q + 1];
    const float4 q4a = ((const float4*)ssq)[2 * q], q4b = ((const float4*)ssq)[2 * q + 1];
    const float4 g4a = ((const float4*)gamma)[2 * q], g4b = ((const float4*)gamma)[2 * q + 1];
    const float4 b4a = ((const float4*)beta)[2 * q], b4b = ((const float4*)beta)[2 * q + 1];
    float h[8], x[8];
    h[0] = __uint_as_float(hv.x << 16);
    h[1] = __uint_as_float(hv.x & 0xffff0000u);
    h[2] = __uint_as_float(hv.y << 16);
    h[3] = __uint_as_float(hv.y & 0xffff0000u);
    h[4] = __uint_as_float(hv.z << 16);
    h[5] = __uint_as_float(hv.z & 0xffff0000u);
    h[6] = __uint_as_float(hv.w << 16);
    h[7] = __uint_as_float(hv.w & 0xffff0000u);
    x[0] = __uint_as_float(xv.x << 16);
    x[1] = __uint_as_float(xv.x & 0xffff0000u);
    x[2] = __uint_as_float(xv.y << 16);
    x[3] = __uint_as_float(xv.y & 0xffff0000u);
    x[4] = __uint_as_float(xv.z << 16);
    x[5] = __uint_as_float(xv.z & 0xffff0000u);
    x[6] = __uint_as_float(xv.w << 16);
    x[7] = __uint_as_float(xv.w & 0xffff0000u);
    float4 oa, ob;
    {
        const float mu = s4a.x * invN, rs = rsqrtf(q4a.x * invN - mu * mu + BN_EPS);
        oa.x = x[0] + (h[0] - mu) * rs * g4a.x + b4a.x;
    }
    {
        const float mu = s4a.y * invN, rs = rsqrtf(q4a.y * invN - mu * mu + BN_EPS);
        oa.y = x[1] + (h[1] - mu) * rs * g4a.y + b4a.y;
    }
    {
        const float mu = s4a.z * invN, rs = rsqrtf(q4a.z * invN - mu * mu + BN_EPS);
        oa.z = x[2] + (h[2] - mu) * rs * g4a.z + b4a.z;
    }
    {
        const float mu = s4a.w * invN, rs = rsqrtf(q4a.w * invN - mu * mu + BN_EPS);
        oa.w = x[3] + (h[3] - mu) * rs * g4a.w + b4a.w;
    }
    {
        const float mu = s4b.x * invN, rs = rsqrtf(q4b.x * invN - mu * mu + BN_EPS);
        ob.x = x[4] + (h[4] - mu) * rs * g4b.x + b4b.x;
    }
    {
        const float mu = s4b.y * invN, rs = rsqrtf(q4b.y * invN - mu * mu + BN_EPS);
        ob.y = x[5] + (h[5] - mu) * rs * g4b.y + b4b.y;
    }
    {
        const float mu = s4b.z * invN, rs = rsqrtf(q4b.z * invN - mu * mu + BN_EPS);
        ob.z = x[6] + (h[6] - mu) * rs * g4b.z + b4b.z;
    }
    {
        const float mu = s4b.w * invN, rs = rsqrtf(q4b.w * invN - mu * mu + BN_EPS);
        ob.w = x[7] + (h[7] - mu) * rs * g4b.w + b4b.w;
    }
    out4[(size_t)node * 32 + 2 * q] = oa;
    out4[(size_t)node * 32 + 2 * q + 1] = ob;
}

extern "C" void kernel_launch(void* const* d_in, const int* in_sizes, int n_in,
                              void* d_out, int out_size, void* d_ws, size_t ws_size,
                              hipStream_t stream) {
    const float* x     = (const float*)d_in[0];
    const void*  ei    = d_in[1];
    const float* Wl    = (const float*)d_in[2];
    const float* bl    = (const float*)d_in[3];
    const float* Wr    = (const float*)d_in[4];
    const float* gamma = (const float*)d_in[5];
    const float* beta  = (const float*)d_in[6];
    float* out = (float*)d_out;

    const int nn = in_sizes[0] / DIM;   // 100000
    const int ne = in_sizes[1] / 2;     // 1600000
    const int nbk = (nn + 255) >> 8;    // 391

    // workspace layout (~72 MB)
    int* ws = (int*)d_ws;
    int*   bcnt    = ws;                 // 512
    float* ssum    = (float*)(ws + 512); // 128
    float* ssq     = (float*)(ws + 640); // 128
    int*   bbase   = ws + 768;           // 512 (nbk+1)
    int*   cursor2 = ws + 1280;          // 512
    int*   cnt     = ws + 1792;          // nn
    int*   off     = cnt + nn;           // nn
    size_t pos = 1792 + 2 * (size_t)nn;
    pos = (pos + 3) & ~(size_t)3;
    uint4* wpack  = (uint4*)(ws + pos);          // 4096 uint4
    int*   srcbuf = (int*)(wpack + 4096);        // ne
    size_t p2 = (size_t)(srcbuf + ne - ws);
    p2 = (p2 + 3) & ~(size_t)3;
    uint2* xf8 = (uint2*)(ws + p2);              // nn*16 uint2 (fp8 rows)
    // union region: pairbuf (passA/passB) then hbuf (gemm/finalize)
    unsigned* pairbuf = (unsigned*)(xf8 + (size_t)nn * 16);  // ne u32
    ushort*   hbuf    = (ushort*)pairbuf;                    // nn*128 bf16 (25.6MB)
    uint4*    xbf     = (uint4*)(hbuf + (size_t)nn * DIM);   // nn*16 uint4 (25.6MB)

    hipMemsetAsync(d_ws, 0, 768 * sizeof(int), stream);  // bcnt + ssum + ssq

    const int PB = (nn * DIM / 8 + 255) / 256;   // 6250
    const int WB = 16;
    const int HB = (ne + 4095) / 4096;           // 391
    k_prep<<<PB + WB + HB, 256, 0, stream>>>((const float4*)x, Wl, Wr,
                                             (const unsigned*)ei, bcnt, xf8, xbf, wpack,
                                             nn, ne, PB, WB);
    k_scanb<<<1, 512, 0, stream>>>(bcnt, bbase, cursor2, nn, ne);
    k_passA<<<(ne + 4095) / 4096, 256, 0, stream>>>((const unsigned*)ei, cursor2,
                                                    pairbuf, nn, ne);
    k_passB<<<nbk, 256, 0, stream>>>(pairbuf, bbase, off, cnt, srcbuf, nn);
    const int ntile = (nn + NB - 1) / NB;        // 3125
    k_gemm<<<ntile, 512, 0, stream>>>(xbf, xf8, wpack, bl,
                                      off, cnt, srcbuf, hbuf, ssum, ssq, nn);
    k_finalize<<<ntile, 512, 0, stream>>>(xbf, (const uint4*)hbuf,
                                          ssum, ssq, gamma, beta, (float4*)out, nn);
}